// Round 10
// baseline (595.692 us; speedup 1.0000x reference)
//
#include <hip/hip_runtime.h>
#include <hip/hip_bf16.h>

// ---------------------------------------------------------------------------
// GATv2 hetero (asset/market). Only layer 1 matters (reference never feeds
// layer outputs forward). Pipeline (4 graph nodes — r9 diagnosis: ~25us per
// dispatch overhead dominated, so CSR build collapsed into one kernel):
//   memset(deg+cursor+bars) -> csr_build (deg|alloc|fill, grid-barriered)
//   -> gemm_all -> gather
// csr_build: homemade device-scope grid barrier; runs alone on the stream;
// grid 1024x256, 0 LDS, tiny VGPR -> co-residency guaranteed (cap 2048).
// Cross-phase reads via atomics (L2) — CDNA L1 is not coherent with other
// CUs' write-through stores within a kernel.
// GEMM: r7/r9 structure (512thr, 64KB LDS; asset blocks 2-phase Wl->XL(bf16),
// Wr->XR; market Wr->XR), swizzle (n&15)<<4 (r8-validated: 0 bank conflicts).
// Split-bf16 MFMA (x = hi+lo, C = Ah*Bh + Al*Bh + Ah*Bl, err ~2^-17).
// XL stored bf16 (halves gather traffic). XR staged in d_out.
// Gather: burst-8, loads hoisted; 32-bit saddr offsets (VALU trim, r9:
// VALUBusy 86% = issue-bound). No-max softmax (scores provably bounded).
// ---------------------------------------------------------------------------

#define NEG_SLOPE 0.2f

typedef __attribute__((ext_vector_type(8))) short short8;
typedef __attribute__((ext_vector_type(4))) float floatx4;
typedef __attribute__((ext_vector_type(4))) unsigned short us4;

// float -> bf16 bits, round-to-nearest-even (with carry)
__device__ inline unsigned short f2bf(float x) {
    union { float f; unsigned u; } v; v.f = x;
    unsigned r = v.u + 0x7FFF + ((v.u >> 16) & 1);
    return (unsigned short)(r >> 16);
}
__device__ inline float bf2f(unsigned short h) {
    union { unsigned u; float f; } v; v.u = (unsigned)h << 16;
    return v.f;
}

// ---- stage W^T (hi/lo bf16, swizzle (n&15)<<4) into 64KB LDS (512 thr) -----
__device__ inline void stage_w(const float* __restrict__ W, unsigned char* lds, int t) {
    const int n = t & 127;
    const int kh = t >> 7;                 // 0..3, k-range kh*32..+32
    unsigned short hb[32], lb[32];
#pragma unroll
    for (int i = 0; i < 32; ++i) {
        int k = kh * 32 + i;
        float w = W[(size_t)k * 128 + n];  // coalesced (n fast across lanes)
        unsigned short h = f2bf(w);
        hb[i] = h;
        lb[i] = f2bf(w - bf2f(h));
    }
#pragma unroll
    for (int j = 0; j < 4; ++j) {          // pack 8 k's -> one b128 write
        int koff = (kh * 32 + j * 8) * 2;
        int off = ((n * 256 + koff) ^ ((n & 15) << 4));
        short8 hv, lv;
#pragma unroll
        for (int i = 0; i < 8; ++i) { hv[i] = (short)hb[j * 8 + i]; lv[i] = (short)lb[j * 8 + i]; }
        *(short8*)(&lds[off]) = hv;
        *(short8*)(&lds[32768 + off]) = lv;
    }
}

// ---- one split-bf16 MFMA pass over the staged W (acc must be zeroed) -------
__device__ inline void mfma_pass(const unsigned char* lds, const short8* ah,
                                 const short8* al, int lr, int lkb, floatx4* acc) {
#pragma unroll
    for (int ks = 0; ks < 4; ++ks) {
#pragma unroll
        for (int ct = 0; ct < 8; ++ct) {
            int n = ct * 16 + lr;
            int off = ((n * 256 + (ks * 32 + lkb) * 2) ^ ((n & 15) << 4));
            short8 bh = *(const short8*)(&lds[off]);
            short8 bl = *(const short8*)(&lds[32768 + off]);
            acc[ct] = __builtin_amdgcn_mfma_f32_16x16x32_bf16(ah[ks], bh, acc[ct], 0, 0, 0);
            acc[ct] = __builtin_amdgcn_mfma_f32_16x16x32_bf16(al[ks], bh, acc[ct], 0, 0, 0);
            acc[ct] = __builtin_amdgcn_mfma_f32_16x16x32_bf16(ah[ks], bl, acc[ct], 0, 0, 0);
        }
    }
}

// ------ merged GEMM: asset blocks (2-phase Wl->XLbf16, Wr->XR) + market -----
__global__ __launch_bounds__(512) void gemm_all(const float* __restrict__ Xa,
                                                const float* __restrict__ Xm,
                                                const float* __restrict__ Wl,
                                                const float* __restrict__ Wr,
                                                unsigned short* __restrict__ XLb,
                                                float* __restrict__ XR,
                                                int Na, int Nm, int nblkA) {
    __shared__ __align__(16) unsigned char lds[65536];  // [0]=hi, [32768]=lo

    const int t = threadIdx.x;
    const int wv = t >> 6;                     // wave 0..7
    const int l = t & 63;
    const int lr = l & 15;                     // A-row / C-col within tile
    const int lkb = (l >> 4) * 8;              // k base within 32-step
    const bool isA = ((int)blockIdx.x < nblkA);
    const int blk = isA ? blockIdx.x : blockIdx.x - nblkA;
    const float* __restrict__ X = isA ? Xa : Xm;
    const int M = isA ? Na : Nm;
    const int arow = blk * 128 + wv * 16 + lr;

    short8 ah[4], al[4];
    if (arow < M) {
#pragma unroll
        for (int ks = 0; ks < 4; ++ks) {
            const float* xp = X + (size_t)arow * 128 + ks * 32 + lkb;
            float4 f0 = *(const float4*)xp;
            float4 f1 = *(const float4*)(xp + 4);
            float xv[8] = {f0.x, f0.y, f0.z, f0.w, f1.x, f1.y, f1.z, f1.w};
            short8 h, lo;
#pragma unroll
            for (int i = 0; i < 8; ++i) {
                unsigned short hb = f2bf(xv[i]);
                h[i] = (short)hb;
                lo[i] = (short)f2bf(xv[i] - bf2f(hb));
            }
            ah[ks] = h; al[ks] = lo;
        }
    } else {
#pragma unroll
        for (int ks = 0; ks < 4; ++ks) { ah[ks] = (short8)0; al[ks] = (short8)0; }
    }

    const int orow0 = blk * 128 + wv * 16 + (l >> 4) * 4;
    floatx4 acc[8];

    if (isA) {
        stage_w(Wl, lds, t);
        __syncthreads();
#pragma unroll
        for (int ct = 0; ct < 8; ++ct) acc[ct] = (floatx4)0.f;
        mfma_pass(lds, ah, al, lr, lkb, acc);
#pragma unroll
        for (int ct = 0; ct < 8; ++ct) {
            int col = ct * 16 + lr;
#pragma unroll
            for (int r = 0; r < 4; ++r) {
                int orow = orow0 + r;
                if (orow < M) XLb[(size_t)orow * 128 + col] = f2bf(acc[ct][r]);
            }
        }
        __syncthreads();                       // all ds_reads of Wl done
        stage_w(Wr, lds, t);
        __syncthreads();
#pragma unroll
        for (int ct = 0; ct < 8; ++ct) acc[ct] = (floatx4)0.f;
        mfma_pass(lds, ah, al, lr, lkb, acc);
#pragma unroll
        for (int ct = 0; ct < 8; ++ct) {
            int col = ct * 16 + lr;
#pragma unroll
            for (int r = 0; r < 4; ++r) {
                int orow = orow0 + r;
                if (orow < M) XR[(size_t)orow * 128 + col] = acc[ct][r];
            }
        }
    } else {
        stage_w(Wr, lds, t);
        __syncthreads();
#pragma unroll
        for (int ct = 0; ct < 8; ++ct) acc[ct] = (floatx4)0.f;
        mfma_pass(lds, ah, al, lr, lkb, acc);
        float* __restrict__ XRm = XR + (size_t)Na * 128;
#pragma unroll
        for (int ct = 0; ct < 8; ++ct) {
            int col = ct * 16 + lr;
#pragma unroll
            for (int r = 0; r < 4; ++r) {
                int orow = orow0 + r;
                if (orow < M) XRm[(size_t)orow * 128 + col] = acc[ct][r];
            }
        }
    }
}

// ------ fused CSR build: degcount | alloc | fillcsr, grid-barriered ---------
// Runs ALONE on the stream; grid=1024x256, 0 LDS, low VGPR -> co-residency
// guaranteed (capacity 2048 blocks), so the spin barrier cannot deadlock.
// deg read in P2 and fill updated in P3 via atomics (L2-coherent); normal
// stores are write-through and fenced before each barrier.
#define GBAR(idx)                                                            \
    __syncthreads();                                                         \
    if (threadIdx.x == 0) {                                                  \
        __threadfence();                                                     \
        atomicAdd(&bars[idx], 1);                                            \
        while (atomicAdd(&bars[idx], 0) < (int)gridDim.x)                    \
            __builtin_amdgcn_s_sleep(16);                                    \
        __threadfence();                                                     \
    }                                                                        \
    __syncthreads();

__global__ __launch_bounds__(256) void csr_build(
        const int* __restrict__ aasrc, const int* __restrict__ aadst,
        const int* __restrict__ amsrc, const int* __restrict__ amdst,
        int* __restrict__ deg, int* __restrict__ cursor,
        int* __restrict__ row_start, int* __restrict__ fill,
        int* __restrict__ csr, int* __restrict__ bars,
        int Eaa, int Eam, int Na, int Ntot) {
    const int nthr = gridDim.x * 256;
    const int tid = blockIdx.x * 256 + threadIdx.x;
    const int nqaa = Eaa >> 2, nqam = Eam >> 2;
    const int remaa = Eaa & 3, remam = Eam & 3;
    const int nitems = nqaa + nqam + remaa + remam;

    // ---- P1: degree count (deg/cursor/bars pre-zeroed by memset node) ----
    for (int i = tid; i < nitems; i += nthr) {
        if (i < nqaa) {
            int4 d = ((const int4*)aadst)[i];
            atomicAdd(&deg[d.x], 1); atomicAdd(&deg[d.y], 1);
            atomicAdd(&deg[d.z], 1); atomicAdd(&deg[d.w], 1);
        } else if (i < nqaa + nqam) {
            int4 d = ((const int4*)amdst)[i - nqaa];
            atomicAdd(&deg[Na + d.x], 1); atomicAdd(&deg[Na + d.y], 1);
            atomicAdd(&deg[Na + d.z], 1); atomicAdd(&deg[Na + d.w], 1);
        } else {
            int k = i - nqaa - nqam;
            if (k < remaa) atomicAdd(&deg[aadst[nqaa * 4 + k]], 1);
            else atomicAdd(&deg[Na + amdst[nqam * 4 + (k - remaa)]], 1);
        }
    }
    GBAR(0)
    // ---- P2: scan-free segment alloc (deg via atomic: bypass stale L1) ----
    for (int i = tid; i < Ntot; i += nthr) {
        int d = atomicAdd(&deg[i], 0);
        int r = atomicAdd(cursor, d);
        row_start[i] = r;
        fill[i] = r;
    }
    GBAR(1)
    // ---- P3: fill csr ----
    for (int i = tid; i < nitems; i += nthr) {
        if (i < nqaa) {
            int4 sv = ((const int4*)aasrc)[i];
            int4 dv = ((const int4*)aadst)[i];
            csr[atomicAdd(&fill[dv.x], 1)] = sv.x;
            csr[atomicAdd(&fill[dv.y], 1)] = sv.y;
            csr[atomicAdd(&fill[dv.z], 1)] = sv.z;
            csr[atomicAdd(&fill[dv.w], 1)] = sv.w;
        } else if (i < nqaa + nqam) {
            int4 sv = ((const int4*)amsrc)[i - nqaa];
            int4 dv = ((const int4*)amdst)[i - nqaa];
            csr[atomicAdd(&fill[Na + dv.x], 1)] = sv.x;
            csr[atomicAdd(&fill[Na + dv.y], 1)] = sv.y;
            csr[atomicAdd(&fill[Na + dv.z], 1)] = sv.z;
            csr[atomicAdd(&fill[Na + dv.w], 1)] = sv.w;
        } else {
            int k = i - nqaa - nqam;
            if (k < remaa)
                csr[atomicAdd(&fill[aadst[nqaa * 4 + k]], 1)] = aasrc[nqaa * 4 + k];
            else
                csr[atomicAdd(&fill[Na + amdst[nqam * 4 + (k - remaa)]], 1)] =
                    amsrc[nqam * 4 + (k - remaa)];
        }
    }
}
#undef GBAR

// ------ fused attention gather: 1 wave/node, burst-8 edges ------------------
// 32-bit saddr offsets ((unsigned)src<<8 fits: Na*256B = 25.6MB), min-clamp
// indices; per-edge weight masked by cndmask.
__global__ __launch_bounds__(256) void gather_gat(const unsigned short* __restrict__ XLb,
                                                  const int* __restrict__ csr,
                                                  const int* __restrict__ row_start,
                                                  const int* __restrict__ deg,
                                                  const float* __restrict__ att,
                                                  const float* __restrict__ bias,
                                                  float* __restrict__ out,
                                                  int Ntot) {
    int wid = (blockIdx.x * 256 + threadIdx.x) >> 6;   // combined node id
    const int l = threadIdx.x & 63;
    if (wid >= Ntot) return;
    const int half = l >> 5;
    const int q = l & 31;                  // channel group: 4q..4q+3
    const unsigned qo = (unsigned)q * 8u;  // byte offset within XL row
    const unsigned char* __restrict__ XLB = (const unsigned char*)XLb;

    const float4 av = *(const float4*)(att + (q >> 3) * 32 + (q & 7) * 4);
    const float4 xr = *(const float4*)(out + (size_t)wid * 128 + q * 4);

    const int beg = row_start[wid];
    const int end = beg + deg[wid];
    const int last = end - 1;
    float s = 0.f;
    float4 acc = make_float4(0.f, 0.f, 0.f, 0.f);

#define EDGE(rv, act)                                                        \
    {                                                                        \
        float x0 = bf2f(rv[0]), x1 = bf2f(rv[1]), x2 = bf2f(rv[2]), x3 = bf2f(rv[3]); \
        float z0 = x0 + xr.x; z0 = fmaxf(z0, NEG_SLOPE * z0);                \
        float z1 = x1 + xr.y; z1 = fmaxf(z1, NEG_SLOPE * z1);                \
        float z2 = x2 + xr.z; z2 = fmaxf(z2, NEG_SLOPE * z2);                \
        float z3 = x3 + xr.w; z3 = fmaxf(z3, NEG_SLOPE * z3);                \
        float p = z0 * av.x;                                                 \
        p = fmaf(z1, av.y, p);                                               \
        p = fmaf(z2, av.z, p);                                               \
        p = fmaf(z3, av.w, p);                                               \
        p += __shfl_xor(p, 1);                                               \
        p += __shfl_xor(p, 2);                                               \
        p += __shfl_xor(p, 4);                                               \
        float w = (act) ? __expf(p) : 0.f;                                   \
        s += w;                                                              \
        acc.x = fmaf(w, x0, acc.x);                                          \
        acc.y = fmaf(w, x1, acc.y);                                          \
        acc.z = fmaf(w, x2, acc.z);                                          \
        acc.w = fmaf(w, x3, acc.w);                                          \
    }

    for (int j = beg; j < end; j += 8) {
        const int b = j + half * 4;
        int s0 = csr[min(b + 0, last)];
        int s1 = csr[min(b + 1, last)];
        int s2 = csr[min(b + 2, last)];
        int s3 = csr[min(b + 3, last)];
        const us4 r0 = *(const us4*)(XLB + (((unsigned)s0 << 8) + qo));
        const us4 r1 = *(const us4*)(XLB + (((unsigned)s1 << 8) + qo));
        const us4 r2 = *(const us4*)(XLB + (((unsigned)s2 << 8) + qo));
        const us4 r3 = *(const us4*)(XLB + (((unsigned)s3 << 8) + qo));
        EDGE(r0, (b + 0) < end);
        EDGE(r1, (b + 1) < end);
        EDGE(r2, (b + 2) < end);
        EDGE(r3, (b + 3) < end);
    }
#undef EDGE

    s += __shfl_xor(s, 32);
    acc.x += __shfl_xor(acc.x, 32);
    acc.y += __shfl_xor(acc.y, 32);
    acc.z += __shfl_xor(acc.z, 32);
    acc.w += __shfl_xor(acc.w, 32);

    if (half == 0) {
        float inv = 1.f / fmaxf(s, 1e-16f);
        const float4 bv = *(const float4*)(bias + q * 4);
        float4 o = make_float4(fmaf(acc.x, inv, bv.x), fmaf(acc.y, inv, bv.y),
                               fmaf(acc.z, inv, bv.z), fmaf(acc.w, inv, bv.w));
        *(float4*)(out + (size_t)wid * 128 + q * 4) = o;
    }
}

// ---------------------------------------------------------------------------
extern "C" void kernel_launch(void* const* d_in, const int* in_sizes, int n_in,
                              void* d_out, int out_size, void* d_ws, size_t ws_size,
                              hipStream_t stream) {
    const float* x_asset  = (const float*)d_in[0];
    const float* x_market = (const float*)d_in[1];
    const int*   eaa      = (const int*)d_in[2];   // [2, Eaa]: src row, dst row
    const int*   eam      = (const int*)d_in[3];   // [2, Eam]
    const float* Wl       = (const float*)d_in[4]; // [2,128,128]
    const float* Wr       = (const float*)d_in[5];
    const float* att      = (const float*)d_in[6]; // [2,4,32]
    const float* bias     = (const float*)d_in[7]; // [2,128]

    const int Na  = in_sizes[0] / 128;
    const int Nm  = in_sizes[1] / 128;
    const int Eaa = in_sizes[2] / 2;
    const int Eam = in_sizes[3] / 2;
    const int Ntot = Na + Nm;

    // Only layer 1 matters (reference overwrites outputs each layer).
    const float* Wl1   = Wl + 128 * 128;
    const float* Wr1   = Wr + 128 * 128;
    const float* att1  = att + 128;
    const float* bias1 = bias + 128;

    // ---- workspace carve (~31MB) ----
    unsigned short* XLb = (unsigned short*)d_ws;     // Na*128 bf16 (25.6MB)
    int*   deg = (int*)(XLb + (size_t)Na * 128);     // Ntot
    int*   cursor = deg + Ntot;                      // 1
    int*   bars = cursor + 1;                        // 8 barrier counters
    int*   fill = bars + 8;                          // Ntot
    int*   row_start = fill + Ntot;                  // Ntot
    int*   csr = row_start + Ntot;                   // E

    float* XR = (float*)d_out;                       // [Ntot,128] staged in out

    // zero deg + cursor + bars (contiguous)
    hipMemsetAsync(deg, 0, sizeof(int) * (size_t)(Ntot + 9), stream);

    csr_build<<<1024, 256, 0, stream>>>(eaa, eaa + Eaa, eam, eam + Eam,
                                        deg, cursor, row_start, fill, csr, bars,
                                        Eaa, Eam, Na, Ntot);

    const int nblkA = (Na + 127) / 128;
    const int nblkM = (Nm + 127) / 128;
    gemm_all<<<nblkA + nblkM, 512, 0, stream>>>(x_asset, x_market, Wl1, Wr1,
                                                XLb, XR, Na, Nm, nblkA);

    gather_gat<<<(Ntot * 64 + 255) / 256, 256, 0, stream>>>(
        XLb, csr, row_start, deg, att1, bias1, (float*)d_out, Ntot);
}